// Round 8
// baseline (424.222 us; speedup 1.0000x reference)
//
#include <hip/hip_runtime.h>
#include <stdint.h>

#define B_ 4
#define N_ 16384
#define D_ 512
#define S_ 512

typedef __attribute__((ext_vector_type(8))) short bf16x8;
typedef __attribute__((ext_vector_type(4))) float f32x4;

__device__ __forceinline__ float bf2f(unsigned short u) {
  union { unsigned int i; float f; } v; v.i = ((unsigned int)u) << 16; return v.f;
}
__device__ __forceinline__ unsigned short f2bf(float f) {
  unsigned int x = __float_as_uint(f);
  return (unsigned short)((x + 0x7FFFu + ((x >> 16) & 1u)) >> 16);
}
__device__ __forceinline__ float ldf(const void* p, long i, bool f32) {
  return f32 ? ((const float*)p)[i] : bf2f(((const unsigned short*)p)[i]);
}
__device__ __forceinline__ void gl_lds16(void* lds_base, const void* g) {
  __builtin_amdgcn_global_load_lds(
      (const __attribute__((address_space(1))) unsigned int*)g,
      (__attribute__((address_space(3))) unsigned int*)lds_base,
      16, 0, 0);
}

__device__ __forceinline__ bool jx_is_i64(const int* jx32) { return jx32[N_ - 1] == 0; }
__device__ __forceinline__ int seg_id(const int* jx32, int n, bool i64) {
  return i64 ? jx32[2 * n] : jx32[n];
}

// ---------------------------------------------------------------------------
// classify_k: dtype sniff (first 2048 elems), ONCE, 1 block.
__global__ __launch_bounds__(256)
void classify_k(const void* __restrict__ x, int* __restrict__ flag) {
  __shared__ int cnt[256];
  int c = 0;
  const unsigned short* xs = (const unsigned short*)x;
#pragma unroll
  for (int i = 0; i < 8; i++) {
    unsigned short w = xs[threadIdx.x * 8 + i];
    int e = (w >> 7) & 0xFF;
    if (e == 0 || (e >= 100 && e <= 140)) c++;
  }
  cnt[threadIdx.x] = c;
  __syncthreads();
  for (int s = 128; s > 0; s >>= 1) {
    if ((int)threadIdx.x < s) cnt[threadIdx.x] += cnt[threadIdx.x + s];
    __syncthreads();
  }
  if (threadIdx.x == 0) flag[0] = (cnt[0] < 1843) ? 1 : 0;
}

// ---------------------------------------------------------------------------
// prep_x (R7: split + grid-stride): x -> xb bf16. 2048 blocks x 8 sweeps
// (was 16384 one-shot blocks) — same traffic, fewer CP block launches,
// full-occupancy TLP.
__global__ __launch_bounds__(256)
void prep_x(const void* __restrict__ x, unsigned short* __restrict__ xb,
            const int* __restrict__ flag) {
  const bool f32 = flag[0] != 0;
  size_t i0 = ((size_t)blockIdx.x * 256 + threadIdx.x) * 8;
  const size_t stride = (size_t)2048 * 256 * 8;
#pragma unroll
  for (int it = 0; it < 8; ++it, i0 += stride) {
    bf16x8 v;
    if (f32) {
      const float4* p = (const float4*)((const float*)x + i0);
      float4 a = p[0], b = p[1];
      v[0]=f2bf(a.x); v[1]=f2bf(a.y); v[2]=f2bf(a.z); v[3]=f2bf(a.w);
      v[4]=f2bf(b.x); v[5]=f2bf(b.y); v[6]=f2bf(b.z); v[7]=f2bf(b.w);
    } else {
      v = *(const bf16x8*)((const unsigned short*)x + i0);
    }
    *(bf16x8*)(xb + i0) = v;
  }
}

// ---------------------------------------------------------------------------
// prep_wseg: [0,3078) weights/biases; [3078,3081) segment bounds.
__global__ __launch_bounds__(256)
void prep_wseg(const int* __restrict__ jx,
               const void* __restrict__ Wf, const void* __restrict__ bfv,
               const void* __restrict__ Wg, const void* __restrict__ bgv,
               const void* __restrict__ Wh, const void* __restrict__ bhv,
               unsigned short* __restrict__ Wfg, unsigned short* __restrict__ biasfg,
               unsigned short* __restrict__ Whb, unsigned short* __restrict__ bhb,
               int* __restrict__ segst, const int* __restrict__ flag) {
  const int blk = blockIdx.x, tid = threadIdx.x;
  if (blk >= 3078) {  // segment bounds via binary search
    int s = (blk - 3078) * 256 + tid;
    if (s > S_) return;
    bool i64 = jx_is_i64(jx);
    int lo = 0, hi = N_;
    while (lo < hi) {
      int mid = (lo + hi) >> 1;
      if (seg_id(jx, mid, i64) < s) lo = mid + 1; else hi = mid;
    }
    segst[s] = lo;
    return;
  }
  const bool f32 = flag[0] != 0;
  int idx = blk * 256 + tid;
  if (idx < 524288) {
    int e = idx >> 9, d = idx & 511;
    float v = (e < 512) ? ldf(Wf, (long)e * 512 + d, f32)
                        : ldf(Wg, (long)(e - 512) * 512 + d, f32);
    Wfg[idx] = f2bf(v);
  } else if (idx < 786432) {
    Whb[idx - 524288] = f2bf(ldf(Wh, idx - 524288, f32));
  } else if (idx < 787456) {
    int j = idx - 786432;
    biasfg[j] = f2bf(j < 512 ? ldf(bfv, j, f32) : ldf(bgv, j - 512, f32));
  } else if (idx < 787968) {
    bhb[idx - 787456] = f2bf(ldf(bhv, idx - 787456, f32));
  }
}

// ---------------------------------------------------------------------------
// fg GEMM (R6-proven: 2-phase 128x128, BK=64, swizzled, 0 bank conflicts).
// R7 change: __launch_bounds__(256,3) — unified regs 88+64=152 <= 170 and
// LDS 32KB x3 <= 160KB, so 3 blocks/CU is feasible; cross-block overlap
// covers the per-barrier vmcnt drain (m114 mechanism).
#define BK 64

__global__ __launch_bounds__(256, 3)
void gemm_fg(const unsigned short* __restrict__ A, const unsigned short* __restrict__ Bm,
             const unsigned short* __restrict__ bias,
             unsigned short* __restrict__ Cf, unsigned short* __restrict__ Cg) {
  __shared__ __align__(16) unsigned short As[128 * BK];
  __shared__ __align__(16) unsigned short Bs[128 * BK];
  const int L = blockIdx.x;
  const int xcd = L & 7, local = L >> 3;
  const int tm = xcd * 64 + local / 8;     // 512 m-tiles -> 64 per XCD
  const int tn = local % 8;
  const int m0 = tm * 128, n0 = tn * 128;

  const int tid  = threadIdx.x;
  const int w    = tid >> 6;
  const int lane = tid & 63;
  const int wm   = w >> 1, wn = w & 1;
  const int l15  = lane & 15, l4 = lane >> 4;
  // staging: round r covers rows r*32 + w*8 + (lane>>3); 16B slot = lane&7,
  // source k-chunk pre-swizzled so LDS slot s' holds chunk s'^(row&7).
  const int srow8 = lane >> 3;                       // row-in-8
  const int ssw   = ((lane & 7) ^ (srow8 & 7)) * 8;  // src elem offset
  const int rsw   = l15 & 7;                         // read swizzle key

  f32x4 acc[4][4];
#pragma unroll
  for (int i = 0; i < 4; i++)
#pragma unroll
    for (int j = 0; j < 4; j++) acc[i][j] = (f32x4){0.f, 0.f, 0.f, 0.f};

  for (int kt = 0; kt < 512; kt += BK) {
    __syncthreads();
#pragma unroll
    for (int r = 0; r < 4; r++) {
      const int rb = r * 32 + w * 8;
      gl_lds16(&As[rb * BK], A  + (size_t)(m0 + rb + srow8) * 512 + kt + ssw);
      gl_lds16(&Bs[rb * BK], Bm + (size_t)(n0 + rb + srow8) * 512 + kt + ssw);
    }
    __syncthreads();

    bf16x8 a[4][2], bb[4][2];
#pragma unroll
    for (int i = 0; i < 4; i++) {
      const int row = wm * 64 + i * 16 + l15;
#pragma unroll
      for (int kk = 0; kk < 2; kk++)
        a[i][kk] = *(const bf16x8*)&As[row * BK + (((l4 + kk * 4) ^ rsw) << 3)];
    }
#pragma unroll
    for (int j = 0; j < 4; j++) {
      const int row = wn * 64 + j * 16 + l15;
#pragma unroll
      for (int kk = 0; kk < 2; kk++)
        bb[j][kk] = *(const bf16x8*)&Bs[row * BK + (((l4 + kk * 4) ^ rsw) << 3)];
    }
#pragma unroll
    for (int i = 0; i < 4; i++)
#pragma unroll
      for (int j = 0; j < 4; j++) {
        acc[i][j] = __builtin_amdgcn_mfma_f32_16x16x32_bf16(a[i][0], bb[j][0], acc[i][j], 0, 0, 0);
        acc[i][j] = __builtin_amdgcn_mfma_f32_16x16x32_bf16(a[i][1], bb[j][1], acc[i][j], 0, 0, 0);
      }
  }

  // epilogue: C/D layout col=lane&15, row=(lane>>4)*4+r; split f (col<512) / g
#pragma unroll
  for (int j = 0; j < 4; j++) {
    const int col = n0 + wn * 64 + j * 16 + l15;
    const float bv = bf2f(bias[col]);
    unsigned short* base = (col < 512) ? Cf : Cg;
    const int cc = col & 511;
#pragma unroll
    for (int i = 0; i < 4; i++) {
      const int rowb = m0 + wm * 64 + i * 16 + l4 * 4;
#pragma unroll
      for (int r = 0; r < 4; r++)
        base[(size_t)(rowb + r) * 512 + cc] = f2bf(acc[i][j][r] + bv);
    }
  }
}

// ---------------------------------------------------------------------------
// Online segment softmax + weighted sum; 2 segments/block, 4 cols/thread.
// R7: row-unroll 2 -> 4 with loads batched first (8 loads in flight/thread).
// Accumulation stays strictly row-ordered -> bit-identical numerics.
#define SM_ROW(fp, gp)                                                        \
  {                                                                           \
    const float ff0 = bf2f((unsigned short)(fp).x), ff1 = bf2f((unsigned short)((fp).x >> 16)); \
    const float ff2 = bf2f((unsigned short)(fp).y), ff3 = bf2f((unsigned short)((fp).y >> 16)); \
    const float gg0 = bf2f((unsigned short)(gp).x), gg1 = bf2f((unsigned short)((gp).x >> 16)); \
    const float gg2 = bf2f((unsigned short)(gp).y), gg3 = bf2f((unsigned short)((gp).y >> 16)); \
    const float e0 = __expf(gg0), e1 = __expf(gg1), e2 = __expf(gg2), e3 = __expf(gg3); \
    den0 += e0; den1 += e1; den2 += e2; den3 += e3;                           \
    y0 += ff0 * e0; y1 += ff1 * e1; y2 += ff2 * e2; y3 += ff3 * e3;           \
  }

__global__ __launch_bounds__(256)
void seg_softmax(const unsigned short* __restrict__ f, const unsigned short* __restrict__ g,
                 const int* __restrict__ segst, unsigned short* __restrict__ y) {
  const int s = blockIdx.x * 2 + (threadIdx.x >> 7);
  const int b = blockIdx.y;
  const int d0 = (threadIdx.x & 127) * 4;
  const int st = segst[s], en = segst[s + 1];
  float den0=0.f, den1=0.f, den2=0.f, den3=0.f;
  float y0=0.f, y1=0.f, y2=0.f, y3=0.f;
  int n = st;
  for (; n + 3 < en; n += 4) {
    const size_t o0 = (size_t)(b * N_ + n) * 512 + d0;
    const uint2 f0v = *(const uint2*)(f + o0);
    const uint2 g0v = *(const uint2*)(g + o0);
    const uint2 f1v = *(const uint2*)(f + o0 + 512);
    const uint2 g1v = *(const uint2*)(g + o0 + 512);
    const uint2 f2v = *(const uint2*)(f + o0 + 1024);
    const uint2 g2v = *(const uint2*)(g + o0 + 1024);
    const uint2 f3v = *(const uint2*)(f + o0 + 1536);
    const uint2 g3v = *(const uint2*)(g + o0 + 1536);
    SM_ROW(f0v, g0v); SM_ROW(f1v, g1v); SM_ROW(f2v, g2v); SM_ROW(f3v, g3v);
  }
  for (; n < en; ++n) {
    const size_t off = (size_t)(b * N_ + n) * 512 + d0;
    const uint2 fp = *(const uint2*)(f + off);
    const uint2 gp = *(const uint2*)(g + off);
    SM_ROW(fp, gp);
  }
  uint2 o;
  if (en > st) {
    o.x = (unsigned int)f2bf(y0 / den0) | ((unsigned int)f2bf(y1 / den1) << 16);
    o.y = (unsigned int)f2bf(y2 / den2) | ((unsigned int)f2bf(y3 / den3) << 16);
  } else { o.x = 0u; o.y = 0u; }
  *(uint2*)(y + (size_t)(b * S_ + s) * 512 + d0) = o;
}

// ---------------------------------------------------------------------------
// hy GEMM: hy[m,c] = sum_k y[m,k]*Whb[c,k] + bhb[c]; 64x64 tiles, 256 blocks.
__global__ __launch_bounds__(256)
void gemm_hy(const unsigned short* __restrict__ y, const unsigned short* __restrict__ Whb,
             const unsigned short* __restrict__ bhb, unsigned short* __restrict__ hy) {
  __shared__ __align__(16) unsigned short As[64 * 32];
  __shared__ __align__(16) unsigned short Bs[64 * 32];
  const int tid = threadIdx.x;
  const int w = tid >> 6, lane = tid & 63;
  const int l15 = lane & 15, l4 = lane >> 4;
  const int m0 = (blockIdx.x >> 3) * 64, c0 = (blockIdx.x & 7) * 64;
  const int srow = lane >> 2, scol = (lane & 3) * 8;

  f32x4 acc[4];
#pragma unroll
  for (int j = 0; j < 4; j++) acc[j] = (f32x4){0.f, 0.f, 0.f, 0.f};

  for (int kt = 0; kt < 512; kt += 32) {
    __syncthreads();
    gl_lds16(&As[(w * 16) * 32], y   + (size_t)(m0 + w * 16 + srow) * 512 + kt + scol);
    gl_lds16(&Bs[(w * 16) * 32], Whb + (size_t)(c0 + w * 16 + srow) * 512 + kt + scol);
    __syncthreads();
    bf16x8 a = *(const bf16x8*)&As[(w * 16 + l15) * 32 + l4 * 8];
#pragma unroll
    for (int j = 0; j < 4; j++) {
      bf16x8 bb = *(const bf16x8*)&Bs[(j * 16 + l15) * 32 + l4 * 8];
      acc[j] = __builtin_amdgcn_mfma_f32_16x16x32_bf16(a, bb, acc[j], 0, 0, 0);
    }
  }
#pragma unroll
  for (int j = 0; j < 4; j++) {
    const float bv = bf2f(bhb[c0 + j * 16 + l15]);
#pragma unroll
    for (int r = 0; r < 4; r++)
      hy[(size_t)(m0 + w * 16 + l4 * 4 + r) * 512 + c0 + j * 16 + l15] =
          f2bf(acc[j][r] + bv);
  }
}

// ---------------------------------------------------------------------------
// out[b,n,:] = hy[b*S + jx[n], :]; one wave per row, vectorized stores.
__global__ __launch_bounds__(256)
void gather_out(const unsigned short* __restrict__ hy, const int* __restrict__ jx,
                void* __restrict__ out, const int* __restrict__ flag) {
  const bool f32 = flag[0] != 0;
  const int gid  = blockIdx.x * 256 + threadIdx.x;
  const int wid  = gid >> 6;
  const int lane = gid & 63;
  const int b = wid >> 14;
  const int n = wid & (N_ - 1);
  const bool i64 = jx_is_i64(jx);
  const int s = seg_id(jx, n, i64);
  const bf16x8 v = *(const bf16x8*)(hy + (size_t)(b * S_ + s) * 512 + lane * 8);
  if (f32) {
    float* dst = (float*)out + (size_t)wid * 512 + lane * 8;
    float4 lo, hi;
    lo.x=bf2f((unsigned short)v[0]); lo.y=bf2f((unsigned short)v[1]);
    lo.z=bf2f((unsigned short)v[2]); lo.w=bf2f((unsigned short)v[3]);
    hi.x=bf2f((unsigned short)v[4]); hi.y=bf2f((unsigned short)v[5]);
    hi.z=bf2f((unsigned short)v[6]); hi.w=bf2f((unsigned short)v[7]);
    *(float4*)dst = lo;
    *(float4*)(dst + 4) = hi;
  } else {
    *(bf16x8*)((unsigned short*)out + (size_t)wid * 512 + lane * 8) = v;
  }
}

// ---------------------------------------------------------------------------
extern "C" void kernel_launch(void* const* d_in, const int* in_sizes, int n_in,
                              void* d_out, int out_size, void* d_ws, size_t ws_size,
                              hipStream_t stream) {
  const void* x  = d_in[0];
  const int* jx  = (const int*)d_in[1];
  const void* Wf = d_in[3];
  const void* bf = d_in[4];
  const void* Wg = d_in[5];
  const void* bg = d_in[6];
  const void* Wh = d_in[7];
  const void* bh = d_in[8];

  // EXACT R3-proven ws layout (ends at 72.4 MB; 80.8 MB was OOB).
  char* ws = (char*)d_ws;
  int* flag              = (int*)(ws + 0);
  int* segst             = (int*)(ws + 4096);
  unsigned short* biasfg = (unsigned short*)(ws + 8192);
  unsigned short* bhb    = (unsigned short*)(ws + 16384);
  unsigned short* Wfg    = (unsigned short*)(ws + 32768);      // 1 MB
  unsigned short* Whb    = (unsigned short*)(ws + 1081344);    // 0.5 MB
  unsigned short* y_ws   = (unsigned short*)(ws + 1605632);    // 2 MB
  unsigned short* hy_ws  = (unsigned short*)(ws + 3702784);    // 2 MB
  unsigned short* xb     = (unsigned short*)(ws + 8388608);    // 64 MB bf16 x
  // f/g (2 x 64 MB bf16) live in d_out (128 MB f32); dead before gather.
  unsigned short* fbuf   = (unsigned short*)d_out;
  unsigned short* gbuf   = (unsigned short*)d_out + (size_t)B_ * N_ * D_;

  classify_k<<<1, 256, 0, stream>>>(x, flag);
  prep_wseg<<<3081, 256, 0, stream>>>(jx, Wf, bf, Wg, bg, Wh, bh,
                                      Wfg, biasfg, Whb, bhb, segst, flag);
  prep_x<<<2048, 256, 0, stream>>>(x, xb, flag);
  gemm_fg<<<4096, 256, 0, stream>>>(xb, Wfg, biasfg, fbuf, gbuf);
  seg_softmax<<<dim3(256, B_), 256, 0, stream>>>(fbuf, gbuf, segst, y_ws);
  gemm_hy<<<256, 256, 0, stream>>>(y_ws, Whb, bhb, hy_ws);
  gather_out<<<16384, 256, 0, stream>>>(hy_ws, jx, d_out, flag);
}

// Round 9
// 385.607 us; speedup vs baseline: 1.1001x; 1.1001x over previous
//
#include <hip/hip_runtime.h>
#include <stdint.h>

#define B_ 4
#define N_ 16384
#define D_ 512
#define S_ 512

typedef __attribute__((ext_vector_type(8))) short bf16x8;
typedef __attribute__((ext_vector_type(4))) float f32x4;

__device__ __forceinline__ float bf2f(unsigned short u) {
  union { unsigned int i; float f; } v; v.i = ((unsigned int)u) << 16; return v.f;
}
__device__ __forceinline__ unsigned short f2bf(float f) {
  unsigned int x = __float_as_uint(f);
  return (unsigned short)((x + 0x7FFFu + ((x >> 16) & 1u)) >> 16);
}
__device__ __forceinline__ float ldf(const void* p, long i, bool f32) {
  return f32 ? ((const float*)p)[i] : bf2f(((const unsigned short*)p)[i]);
}
__device__ __forceinline__ void gl_lds16(void* lds_base, const void* g) {
  __builtin_amdgcn_global_load_lds(
      (const __attribute__((address_space(1))) unsigned int*)g,
      (__attribute__((address_space(3))) unsigned int*)lds_base,
      16, 0, 0);
}

__device__ __forceinline__ bool jx_is_i64(const int* jx32) { return jx32[N_ - 1] == 0; }
__device__ __forceinline__ int seg_id(const int* jx32, int n, bool i64) {
  return i64 ? jx32[2 * n] : jx32[n];
}

// ---------------------------------------------------------------------------
// classify_k: dtype sniff (first 2048 elems), ONCE, 1 block.
__global__ __launch_bounds__(256)
void classify_k(const void* __restrict__ x, int* __restrict__ flag) {
  __shared__ int cnt[256];
  int c = 0;
  const unsigned short* xs = (const unsigned short*)x;
#pragma unroll
  for (int i = 0; i < 8; i++) {
    unsigned short w = xs[threadIdx.x * 8 + i];
    int e = (w >> 7) & 0xFF;
    if (e == 0 || (e >= 100 && e <= 140)) c++;
  }
  cnt[threadIdx.x] = c;
  __syncthreads();
  for (int s = 128; s > 0; s >>= 1) {
    if ((int)threadIdx.x < s) cnt[threadIdx.x] += cnt[threadIdx.x + s];
    __syncthreads();
  }
  if (threadIdx.x == 0) flag[0] = (cnt[0] < 1843) ? 1 : 0;
}

// ---------------------------------------------------------------------------
// prep_x: x -> xb bf16. 2048 blocks x 8 grid-stride sweeps.
__global__ __launch_bounds__(256)
void prep_x(const void* __restrict__ x, unsigned short* __restrict__ xb,
            const int* __restrict__ flag) {
  const bool f32 = flag[0] != 0;
  size_t i0 = ((size_t)blockIdx.x * 256 + threadIdx.x) * 8;
  const size_t stride = (size_t)2048 * 256 * 8;
#pragma unroll
  for (int it = 0; it < 8; ++it, i0 += stride) {
    bf16x8 v;
    if (f32) {
      const float4* p = (const float4*)((const float*)x + i0);
      float4 a = p[0], b = p[1];
      v[0]=f2bf(a.x); v[1]=f2bf(a.y); v[2]=f2bf(a.z); v[3]=f2bf(a.w);
      v[4]=f2bf(b.x); v[5]=f2bf(b.y); v[6]=f2bf(b.z); v[7]=f2bf(b.w);
    } else {
      v = *(const bf16x8*)((const unsigned short*)x + i0);
    }
    *(bf16x8*)(xb + i0) = v;
  }
}

// ---------------------------------------------------------------------------
// prep_wseg: [0,3078) weights/biases; [3078,3081) segment bounds.
__global__ __launch_bounds__(256)
void prep_wseg(const int* __restrict__ jx,
               const void* __restrict__ Wf, const void* __restrict__ bfv,
               const void* __restrict__ Wg, const void* __restrict__ bgv,
               const void* __restrict__ Wh, const void* __restrict__ bhv,
               unsigned short* __restrict__ Wfg, unsigned short* __restrict__ biasfg,
               unsigned short* __restrict__ Whb, unsigned short* __restrict__ bhb,
               int* __restrict__ segst, const int* __restrict__ flag) {
  const int blk = blockIdx.x, tid = threadIdx.x;
  if (blk >= 3078) {  // segment bounds via binary search
    int s = (blk - 3078) * 256 + tid;
    if (s > S_) return;
    bool i64 = jx_is_i64(jx);
    int lo = 0, hi = N_;
    while (lo < hi) {
      int mid = (lo + hi) >> 1;
      if (seg_id(jx, mid, i64) < s) lo = mid + 1; else hi = mid;
    }
    segst[s] = lo;
    return;
  }
  const bool f32 = flag[0] != 0;
  int idx = blk * 256 + tid;
  if (idx < 524288) {
    int e = idx >> 9, d = idx & 511;
    float v = (e < 512) ? ldf(Wf, (long)e * 512 + d, f32)
                        : ldf(Wg, (long)(e - 512) * 512 + d, f32);
    Wfg[idx] = f2bf(v);
  } else if (idx < 786432) {
    Whb[idx - 524288] = f2bf(ldf(Wh, idx - 524288, f32));
  } else if (idx < 787456) {
    int j = idx - 786432;
    biasfg[j] = f2bf(j < 512 ? ldf(bfv, j, f32) : ldf(bgv, j - 512, f32));
  } else if (idx < 787968) {
    bhb[idx - 787456] = f2bf(ldf(bhv, idx - 787456, f32));
  }
}

// ---------------------------------------------------------------------------
// fg GEMM — EXACT R6 champion config: 2-phase 128x128, BK=64, swizzled,
// 0 bank conflicts, __launch_bounds__(256,2).
// R8 lesson: (256,3) doubled FETCH+WRITE (L2 overflow + broken store
// write-combining at 768 resident blocks) and cost 40%. 2 blocks/CU is the
// locality sweet spot for this tile shape.
#define BK 64

__global__ __launch_bounds__(256, 2)
void gemm_fg(const unsigned short* __restrict__ A, const unsigned short* __restrict__ Bm,
             const unsigned short* __restrict__ bias,
             unsigned short* __restrict__ Cf, unsigned short* __restrict__ Cg) {
  __shared__ __align__(16) unsigned short As[128 * BK];
  __shared__ __align__(16) unsigned short Bs[128 * BK];
  const int L = blockIdx.x;
  const int xcd = L & 7, local = L >> 3;
  const int tm = xcd * 64 + local / 8;     // 512 m-tiles -> 64 per XCD
  const int tn = local % 8;
  const int m0 = tm * 128, n0 = tn * 128;

  const int tid  = threadIdx.x;
  const int w    = tid >> 6;
  const int lane = tid & 63;
  const int wm   = w >> 1, wn = w & 1;
  const int l15  = lane & 15, l4 = lane >> 4;
  // staging: round r covers rows r*32 + w*8 + (lane>>3); 16B slot = lane&7,
  // source k-chunk pre-swizzled so LDS slot s' holds chunk s'^(row&7).
  const int srow8 = lane >> 3;                       // row-in-8
  const int ssw   = ((lane & 7) ^ (srow8 & 7)) * 8;  // src elem offset
  const int rsw   = l15 & 7;                         // read swizzle key

  f32x4 acc[4][4];
#pragma unroll
  for (int i = 0; i < 4; i++)
#pragma unroll
    for (int j = 0; j < 4; j++) acc[i][j] = (f32x4){0.f, 0.f, 0.f, 0.f};

  for (int kt = 0; kt < 512; kt += BK) {
    __syncthreads();
#pragma unroll
    for (int r = 0; r < 4; r++) {
      const int rb = r * 32 + w * 8;
      gl_lds16(&As[rb * BK], A  + (size_t)(m0 + rb + srow8) * 512 + kt + ssw);
      gl_lds16(&Bs[rb * BK], Bm + (size_t)(n0 + rb + srow8) * 512 + kt + ssw);
    }
    __syncthreads();

    bf16x8 a[4][2], bb[4][2];
#pragma unroll
    for (int i = 0; i < 4; i++) {
      const int row = wm * 64 + i * 16 + l15;
#pragma unroll
      for (int kk = 0; kk < 2; kk++)
        a[i][kk] = *(const bf16x8*)&As[row * BK + (((l4 + kk * 4) ^ rsw) << 3)];
    }
#pragma unroll
    for (int j = 0; j < 4; j++) {
      const int row = wn * 64 + j * 16 + l15;
#pragma unroll
      for (int kk = 0; kk < 2; kk++)
        bb[j][kk] = *(const bf16x8*)&Bs[row * BK + (((l4 + kk * 4) ^ rsw) << 3)];
    }
#pragma unroll
    for (int i = 0; i < 4; i++)
#pragma unroll
      for (int j = 0; j < 4; j++) {
        acc[i][j] = __builtin_amdgcn_mfma_f32_16x16x32_bf16(a[i][0], bb[j][0], acc[i][j], 0, 0, 0);
        acc[i][j] = __builtin_amdgcn_mfma_f32_16x16x32_bf16(a[i][1], bb[j][1], acc[i][j], 0, 0, 0);
      }
  }

  // epilogue: C/D layout col=lane&15, row=(lane>>4)*4+r; split f (col<512) / g
#pragma unroll
  for (int j = 0; j < 4; j++) {
    const int col = n0 + wn * 64 + j * 16 + l15;
    const float bv = bf2f(bias[col]);
    unsigned short* base = (col < 512) ? Cf : Cg;
    const int cc = col & 511;
#pragma unroll
    for (int i = 0; i < 4; i++) {
      const int rowb = m0 + wm * 64 + i * 16 + l4 * 4;
#pragma unroll
      for (int r = 0; r < 4; r++)
        base[(size_t)(rowb + r) * 512 + cc] = f2bf(acc[i][j][r] + bv);
    }
  }
}

// ---------------------------------------------------------------------------
// Online segment softmax + weighted sum; 2 segments/block, 4 cols/thread.
// Row-unroll 4 with loads batched first. Row-ordered accumulation.
#define SM_ROW(fp, gp)                                                        \
  {                                                                           \
    const float ff0 = bf2f((unsigned short)(fp).x), ff1 = bf2f((unsigned short)((fp).x >> 16)); \
    const float ff2 = bf2f((unsigned short)(fp).y), ff3 = bf2f((unsigned short)((fp).y >> 16)); \
    const float gg0 = bf2f((unsigned short)(gp).x), gg1 = bf2f((unsigned short)((gp).x >> 16)); \
    const float gg2 = bf2f((unsigned short)(gp).y), gg3 = bf2f((unsigned short)((gp).y >> 16)); \
    const float e0 = __expf(gg0), e1 = __expf(gg1), e2 = __expf(gg2), e3 = __expf(gg3); \
    den0 += e0; den1 += e1; den2 += e2; den3 += e3;                           \
    y0 += ff0 * e0; y1 += ff1 * e1; y2 += ff2 * e2; y3 += ff3 * e3;           \
  }

__global__ __launch_bounds__(256)
void seg_softmax(const unsigned short* __restrict__ f, const unsigned short* __restrict__ g,
                 const int* __restrict__ segst, unsigned short* __restrict__ y) {
  const int s = blockIdx.x * 2 + (threadIdx.x >> 7);
  const int b = blockIdx.y;
  const int d0 = (threadIdx.x & 127) * 4;
  const int st = segst[s], en = segst[s + 1];
  float den0=0.f, den1=0.f, den2=0.f, den3=0.f;
  float y0=0.f, y1=0.f, y2=0.f, y3=0.f;
  int n = st;
  for (; n + 3 < en; n += 4) {
    const size_t o0 = (size_t)(b * N_ + n) * 512 + d0;
    const uint2 f0v = *(const uint2*)(f + o0);
    const uint2 g0v = *(const uint2*)(g + o0);
    const uint2 f1v = *(const uint2*)(f + o0 + 512);
    const uint2 g1v = *(const uint2*)(g + o0 + 512);
    const uint2 f2v = *(const uint2*)(f + o0 + 1024);
    const uint2 g2v = *(const uint2*)(g + o0 + 1024);
    const uint2 f3v = *(const uint2*)(f + o0 + 1536);
    const uint2 g3v = *(const uint2*)(g + o0 + 1536);
    SM_ROW(f0v, g0v); SM_ROW(f1v, g1v); SM_ROW(f2v, g2v); SM_ROW(f3v, g3v);
  }
  for (; n < en; ++n) {
    const size_t off = (size_t)(b * N_ + n) * 512 + d0;
    const uint2 fp = *(const uint2*)(f + off);
    const uint2 gp = *(const uint2*)(g + off);
    SM_ROW(fp, gp);
  }
  uint2 o;
  if (en > st) {
    o.x = (unsigned int)f2bf(y0 / den0) | ((unsigned int)f2bf(y1 / den1) << 16);
    o.y = (unsigned int)f2bf(y2 / den2) | ((unsigned int)f2bf(y3 / den3) << 16);
  } else { o.x = 0u; o.y = 0u; }
  *(uint2*)(y + (size_t)(b * S_ + s) * 512 + d0) = o;
}

// ---------------------------------------------------------------------------
// hy GEMM: hy[m,c] = sum_k y[m,k]*Whb[c,k] + bhb[c]; 64x64 tiles, 256 blocks.
__global__ __launch_bounds__(256)
void gemm_hy(const unsigned short* __restrict__ y, const unsigned short* __restrict__ Whb,
             const unsigned short* __restrict__ bhb, unsigned short* __restrict__ hy) {
  __shared__ __align__(16) unsigned short As[64 * 32];
  __shared__ __align__(16) unsigned short Bs[64 * 32];
  const int tid = threadIdx.x;
  const int w = tid >> 6, lane = tid & 63;
  const int l15 = lane & 15, l4 = lane >> 4;
  const int m0 = (blockIdx.x >> 3) * 64, c0 = (blockIdx.x & 7) * 64;
  const int srow = lane >> 2, scol = (lane & 3) * 8;

  f32x4 acc[4];
#pragma unroll
  for (int j = 0; j < 4; j++) acc[j] = (f32x4){0.f, 0.f, 0.f, 0.f};

  for (int kt = 0; kt < 512; kt += 32) {
    __syncthreads();
    gl_lds16(&As[(w * 16) * 32], y   + (size_t)(m0 + w * 16 + srow) * 512 + kt + scol);
    gl_lds16(&Bs[(w * 16) * 32], Whb + (size_t)(c0 + w * 16 + srow) * 512 + kt + scol);
    __syncthreads();
    bf16x8 a = *(const bf16x8*)&As[(w * 16 + l15) * 32 + l4 * 8];
#pragma unroll
    for (int j = 0; j < 4; j++) {
      bf16x8 bb = *(const bf16x8*)&Bs[(j * 16 + l15) * 32 + l4 * 8];
      acc[j] = __builtin_amdgcn_mfma_f32_16x16x32_bf16(a, bb, acc[j], 0, 0, 0);
    }
  }
#pragma unroll
  for (int j = 0; j < 4; j++) {
    const float bv = bf2f(bhb[c0 + j * 16 + l15]);
#pragma unroll
    for (int r = 0; r < 4; r++)
      hy[(size_t)(m0 + w * 16 + l4 * 4 + r) * 512 + c0 + j * 16 + l15] =
          f2bf(acc[j][r] + bv);
  }
}

// ---------------------------------------------------------------------------
// out[b,n,:] = hy[b*S + jx[n], :]; one wave per row, vectorized stores.
__global__ __launch_bounds__(256)
void gather_out(const unsigned short* __restrict__ hy, const int* __restrict__ jx,
                void* __restrict__ out, const int* __restrict__ flag) {
  const bool f32 = flag[0] != 0;
  const int gid  = blockIdx.x * 256 + threadIdx.x;
  const int wid  = gid >> 6;
  const int lane = gid & 63;
  const int b = wid >> 14;
  const int n = wid & (N_ - 1);
  const bool i64 = jx_is_i64(jx);
  const int s = seg_id(jx, n, i64);
  const bf16x8 v = *(const bf16x8*)(hy + (size_t)(b * S_ + s) * 512 + lane * 8);
  if (f32) {
    float* dst = (float*)out + (size_t)wid * 512 + lane * 8;
    float4 lo, hi;
    lo.x=bf2f((unsigned short)v[0]); lo.y=bf2f((unsigned short)v[1]);
    lo.z=bf2f((unsigned short)v[2]); lo.w=bf2f((unsigned short)v[3]);
    hi.x=bf2f((unsigned short)v[4]); hi.y=bf2f((unsigned short)v[5]);
    hi.z=bf2f((unsigned short)v[6]); hi.w=bf2f((unsigned short)v[7]);
    *(float4*)dst = lo;
    *(float4*)(dst + 4) = hi;
  } else {
    *(bf16x8*)((unsigned short*)out + (size_t)wid * 512 + lane * 8) = v;
  }
}

// ---------------------------------------------------------------------------
extern "C" void kernel_launch(void* const* d_in, const int* in_sizes, int n_in,
                              void* d_out, int out_size, void* d_ws, size_t ws_size,
                              hipStream_t stream) {
  const void* x  = d_in[0];
  const int* jx  = (const int*)d_in[1];
  const void* Wf = d_in[3];
  const void* bf = d_in[4];
  const void* Wg = d_in[5];
  const void* bg = d_in[6];
  const void* Wh = d_in[7];
  const void* bh = d_in[8];

  // EXACT R3-proven ws layout (ends at 72.4 MB; 80.8 MB was OOB).
  char* ws = (char*)d_ws;
  int* flag              = (int*)(ws + 0);
  int* segst             = (int*)(ws + 4096);
  unsigned short* biasfg = (unsigned short*)(ws + 8192);
  unsigned short* bhb    = (unsigned short*)(ws + 16384);
  unsigned short* Wfg    = (unsigned short*)(ws + 32768);      // 1 MB
  unsigned short* Whb    = (unsigned short*)(ws + 1081344);    // 0.5 MB
  unsigned short* y_ws   = (unsigned short*)(ws + 1605632);    // 2 MB
  unsigned short* hy_ws  = (unsigned short*)(ws + 3702784);    // 2 MB
  unsigned short* xb     = (unsigned short*)(ws + 8388608);    // 64 MB bf16 x
  // f/g (2 x 64 MB bf16) live in d_out (128 MB f32); dead before gather.
  unsigned short* fbuf   = (unsigned short*)d_out;
  unsigned short* gbuf   = (unsigned short*)d_out + (size_t)B_ * N_ * D_;

  classify_k<<<1, 256, 0, stream>>>(x, flag);
  prep_wseg<<<3081, 256, 0, stream>>>(jx, Wf, bf, Wg, bg, Wh, bh,
                                      Wfg, biasfg, Whb, bhb, segst, flag);
  prep_x<<<2048, 256, 0, stream>>>(x, xb, flag);
  gemm_fg<<<4096, 256, 0, stream>>>(xb, Wfg, biasfg, fbuf, gbuf);
  seg_softmax<<<dim3(256, B_), 256, 0, stream>>>(fbuf, gbuf, segst, y_ws);
  gemm_hy<<<256, 256, 0, stream>>>(y_ws, Whb, bhb, hy_ws);
  gather_out<<<16384, 256, 0, stream>>>(hy_ws, jx, d_out, flag);
}

// Round 10
// 384.863 us; speedup vs baseline: 1.1023x; 1.0019x over previous
//
#include <hip/hip_runtime.h>
#include <stdint.h>

#define B_ 4
#define N_ 16384
#define D_ 512
#define S_ 512

typedef __attribute__((ext_vector_type(8))) short bf16x8;
typedef __attribute__((ext_vector_type(4))) float f32x4;

__device__ __forceinline__ float bf2f(unsigned short u) {
  union { unsigned int i; float f; } v; v.i = ((unsigned int)u) << 16; return v.f;
}
__device__ __forceinline__ unsigned short f2bf(float f) {
  unsigned int x = __float_as_uint(f);
  return (unsigned short)((x + 0x7FFFu + ((x >> 16) & 1u)) >> 16);
}
__device__ __forceinline__ float ldf(const void* p, long i, bool f32) {
  return f32 ? ((const float*)p)[i] : bf2f(((const unsigned short*)p)[i]);
}
__device__ __forceinline__ void gl_lds16(void* lds_base, const void* g) {
  __builtin_amdgcn_global_load_lds(
      (const __attribute__((address_space(1))) unsigned int*)g,
      (__attribute__((address_space(3))) unsigned int*)lds_base,
      16, 0, 0);
}

__device__ __forceinline__ bool jx_is_i64(const int* jx32) { return jx32[N_ - 1] == 0; }
__device__ __forceinline__ int seg_id(const int* jx32, int n, bool i64) {
  return i64 ? jx32[2 * n] : jx32[n];
}

// ---------------------------------------------------------------------------
// classify_k: dtype sniff (first 2048 elems), ONCE, 1 block.
__global__ __launch_bounds__(256)
void classify_k(const void* __restrict__ x, int* __restrict__ flag) {
  __shared__ int cnt[256];
  int c = 0;
  const unsigned short* xs = (const unsigned short*)x;
#pragma unroll
  for (int i = 0; i < 8; i++) {
    unsigned short w = xs[threadIdx.x * 8 + i];
    int e = (w >> 7) & 0xFF;
    if (e == 0 || (e >= 100 && e <= 140)) c++;
  }
  cnt[threadIdx.x] = c;
  __syncthreads();
  for (int s = 128; s > 0; s >>= 1) {
    if ((int)threadIdx.x < s) cnt[threadIdx.x] += cnt[threadIdx.x + s];
    __syncthreads();
  }
  if (threadIdx.x == 0) flag[0] = (cnt[0] < 1843) ? 1 : 0;
}

// ---------------------------------------------------------------------------
// prep_all (R6 champion config): [0,16384) x -> xb bf16; [16384,19462)
// weights/biases; [19462,19465) segment bounds. Reads flag (uniform).
// R9 lesson: splitting into 3 kernels added launch boundaries for ~nothing.
__global__ __launch_bounds__(256)
void prep_all(const void* __restrict__ x, const int* __restrict__ jx,
              const void* __restrict__ Wf, const void* __restrict__ bfv,
              const void* __restrict__ Wg, const void* __restrict__ bgv,
              const void* __restrict__ Wh, const void* __restrict__ bhv,
              unsigned short* __restrict__ xb, unsigned short* __restrict__ Wfg,
              unsigned short* __restrict__ biasfg, unsigned short* __restrict__ Whb,
              unsigned short* __restrict__ bhb, int* __restrict__ segst,
              const int* __restrict__ flag) {
  const int blk = blockIdx.x, tid = threadIdx.x;
  if (blk >= 19462) {  // segment bounds via binary search
    int s = (blk - 19462) * 256 + tid;
    if (s > S_) return;
    bool i64 = jx_is_i64(jx);
    int lo = 0, hi = N_;
    while (lo < hi) {
      int mid = (lo + hi) >> 1;
      if (seg_id(jx, mid, i64) < s) lo = mid + 1; else hi = mid;
    }
    segst[s] = lo;
    return;
  }
  const bool f32 = flag[0] != 0;
  if (blk < 16384) {  // x -> bf16
    const size_t i0 = ((size_t)blk * 256 + tid) * 8;
    bf16x8 v;
    if (f32) {
      const float4* p = (const float4*)((const float*)x + i0);
      float4 a = p[0], b = p[1];
      v[0]=f2bf(a.x); v[1]=f2bf(a.y); v[2]=f2bf(a.z); v[3]=f2bf(a.w);
      v[4]=f2bf(b.x); v[5]=f2bf(b.y); v[6]=f2bf(b.z); v[7]=f2bf(b.w);
    } else {
      v = *(const bf16x8*)((const unsigned short*)x + i0);
    }
    *(bf16x8*)(xb + i0) = v;
  } else {  // weights / biases
    int idx = (blk - 16384) * 256 + tid;
    if (idx < 524288) {
      int e = idx >> 9, d = idx & 511;
      float v = (e < 512) ? ldf(Wf, (long)e * 512 + d, f32)
                          : ldf(Wg, (long)(e - 512) * 512 + d, f32);
      Wfg[idx] = f2bf(v);
    } else if (idx < 786432) {
      Whb[idx - 524288] = f2bf(ldf(Wh, idx - 524288, f32));
    } else if (idx < 787456) {
      int j = idx - 786432;
      biasfg[j] = f2bf(j < 512 ? ldf(bfv, j, f32) : ldf(bgv, j - 512, f32));
    } else if (idx < 787968) {
      bhb[idx - 787456] = f2bf(ldf(bhv, idx - 787456, f32));
    }
  }
}

// ---------------------------------------------------------------------------
// fg GEMM — R10 change: BK 64 -> 128 on the proven 2-phase 128x128 structure.
// 4 K-steps instead of 8 => barrier-pair count halves again (the structural
// stall of the 2-phase loop). We are already pinned at 2 blocks/CU, so the
// m132 occupancy-drop failure mode doesn't apply (LDS 64KB x2 = 128 <= 160).
// LDS layout: [128 rows][16 slots of 16B], slot s' holds k-chunk s'^(row&15)
// => 2-way (free) bank access on stage and read. Inner loop: q = 0..3
// ascending k-chunks -> bit-identical accumulation order.
#define BK 128

__global__ __launch_bounds__(256, 2)
void gemm_fg(const unsigned short* __restrict__ A, const unsigned short* __restrict__ Bm,
             const unsigned short* __restrict__ bias,
             unsigned short* __restrict__ Cf, unsigned short* __restrict__ Cg) {
  __shared__ __align__(16) unsigned short As[128 * BK];
  __shared__ __align__(16) unsigned short Bs[128 * BK];
  const int L = blockIdx.x;
  const int xcd = L & 7, local = L >> 3;
  const int tm = xcd * 64 + local / 8;     // 512 m-tiles -> 64 per XCD
  const int tn = local % 8;
  const int m0 = tm * 128, n0 = tn * 128;

  const int tid  = threadIdx.x;
  const int w    = tid >> 6;
  const int lane = tid & 63;
  const int wm   = w >> 1, wn = w & 1;
  const int l15  = lane & 15, l4 = lane >> 4;
  // staging: round r covers rows r*16 + w*4 + (lane>>4); slot = lane&15.
  // LDS dest linear in lane (row*256B + slot*16B = base + lane*16B).
  const int srow16 = lane >> 4;            // row-in-4 within wave
  const int sslot  = lane & 15;

  f32x4 acc[4][4];
#pragma unroll
  for (int i = 0; i < 4; i++)
#pragma unroll
    for (int j = 0; j < 4; j++) acc[i][j] = (f32x4){0.f, 0.f, 0.f, 0.f};

  for (int kt = 0; kt < 512; kt += BK) {
    __syncthreads();
#pragma unroll
    for (int r = 0; r < 8; r++) {
      const int row = r * 16 + w * 4 + srow16;
      const int src = kt + ((sslot ^ (row & 15)) << 3);  // pre-swizzled chunk
      gl_lds16(&As[row * BK + sslot * 8], A  + (size_t)(m0 + row) * 512 + src);
      gl_lds16(&Bs[row * BK + sslot * 8], Bm + (size_t)(n0 + row) * 512 + src);
    }
    __syncthreads();

#pragma unroll
    for (int q = 0; q < 4; q++) {  // ascending k-chunks: bit-identical order
      const int slot = ((q * 4 + l4) ^ l15) << 3;
      bf16x8 a[4], bb[4];
#pragma unroll
      for (int i = 0; i < 4; i++)
        a[i] = *(const bf16x8*)&As[(wm * 64 + i * 16 + l15) * BK + slot];
#pragma unroll
      for (int j = 0; j < 4; j++)
        bb[j] = *(const bf16x8*)&Bs[(wn * 64 + j * 16 + l15) * BK + slot];
#pragma unroll
      for (int i = 0; i < 4; i++)
#pragma unroll
        for (int j = 0; j < 4; j++)
          acc[i][j] = __builtin_amdgcn_mfma_f32_16x16x32_bf16(a[i], bb[j], acc[i][j], 0, 0, 0);
    }
  }

  // epilogue: C/D layout col=lane&15, row=(lane>>4)*4+r; split f (col<512) / g
#pragma unroll
  for (int j = 0; j < 4; j++) {
    const int col = n0 + wn * 64 + j * 16 + l15;
    const float bv = bf2f(bias[col]);
    unsigned short* base = (col < 512) ? Cf : Cg;
    const int cc = col & 511;
#pragma unroll
    for (int i = 0; i < 4; i++) {
      const int rowb = m0 + wm * 64 + i * 16 + l4 * 4;
#pragma unroll
      for (int r = 0; r < 4; r++)
        base[(size_t)(rowb + r) * 512 + cc] = f2bf(acc[i][j][r] + bv);
    }
  }
}

// ---------------------------------------------------------------------------
// Online segment softmax + weighted sum (R6 champion version); 2 segments/
// block, 4 cols/thread, n-loop unrolled by 2. |g| < ~7 so no max subtraction.
__global__ __launch_bounds__(256)
void seg_softmax(const unsigned short* __restrict__ f, const unsigned short* __restrict__ g,
                 const int* __restrict__ segst, unsigned short* __restrict__ y) {
  const int s = blockIdx.x * 2 + (threadIdx.x >> 7);
  const int b = blockIdx.y;
  const int d0 = (threadIdx.x & 127) * 4;
  const int st = segst[s], en = segst[s + 1];
  float den0=0.f, den1=0.f, den2=0.f, den3=0.f;
  float y0=0.f, y1=0.f, y2=0.f, y3=0.f;
  int n = st;
  for (; n + 1 < en; n += 2) {
    const size_t offA = (size_t)(b * N_ + n) * 512 + d0;
    const size_t offB = offA + 512;
    const uint2 fpA = *(const uint2*)(f + offA);
    const uint2 gpA = *(const uint2*)(g + offA);
    const uint2 fpB = *(const uint2*)(f + offB);
    const uint2 gpB = *(const uint2*)(g + offB);
    {
      const float f0 = bf2f((unsigned short)fpA.x), f1 = bf2f((unsigned short)(fpA.x >> 16));
      const float f2 = bf2f((unsigned short)fpA.y), f3 = bf2f((unsigned short)(fpA.y >> 16));
      const float g0 = bf2f((unsigned short)gpA.x), g1 = bf2f((unsigned short)(gpA.x >> 16));
      const float g2 = bf2f((unsigned short)gpA.y), g3 = bf2f((unsigned short)(gpA.y >> 16));
      const float e0 = __expf(g0), e1 = __expf(g1), e2 = __expf(g2), e3 = __expf(g3);
      den0 += e0; den1 += e1; den2 += e2; den3 += e3;
      y0 += f0 * e0; y1 += f1 * e1; y2 += f2 * e2; y3 += f3 * e3;
    }
    {
      const float f0 = bf2f((unsigned short)fpB.x), f1 = bf2f((unsigned short)(fpB.x >> 16));
      const float f2 = bf2f((unsigned short)fpB.y), f3 = bf2f((unsigned short)(fpB.y >> 16));
      const float g0 = bf2f((unsigned short)gpB.x), g1 = bf2f((unsigned short)(gpB.x >> 16));
      const float g2 = bf2f((unsigned short)gpB.y), g3 = bf2f((unsigned short)(gpB.y >> 16));
      const float e0 = __expf(g0), e1 = __expf(g1), e2 = __expf(g2), e3 = __expf(g3);
      den0 += e0; den1 += e1; den2 += e2; den3 += e3;
      y0 += f0 * e0; y1 += f1 * e1; y2 += f2 * e2; y3 += f3 * e3;
    }
  }
  if (n < en) {
    const size_t off = (size_t)(b * N_ + n) * 512 + d0;
    const uint2 fp = *(const uint2*)(f + off);
    const uint2 gp = *(const uint2*)(g + off);
    const float f0 = bf2f((unsigned short)fp.x), f1 = bf2f((unsigned short)(fp.x >> 16));
    const float f2 = bf2f((unsigned short)fp.y), f3 = bf2f((unsigned short)(fp.y >> 16));
    const float g0 = bf2f((unsigned short)gp.x), g1 = bf2f((unsigned short)(gp.x >> 16));
    const float g2 = bf2f((unsigned short)gp.y), g3 = bf2f((unsigned short)(gp.y >> 16));
    const float e0 = __expf(g0), e1 = __expf(g1), e2 = __expf(g2), e3 = __expf(g3);
    den0 += e0; den1 += e1; den2 += e2; den3 += e3;
    y0 += f0 * e0; y1 += f1 * e1; y2 += f2 * e2; y3 += f3 * e3;
  }
  uint2 o;
  if (en > st) {
    o.x = (unsigned int)f2bf(y0 / den0) | ((unsigned int)f2bf(y1 / den1) << 16);
    o.y = (unsigned int)f2bf(y2 / den2) | ((unsigned int)f2bf(y3 / den3) << 16);
  } else { o.x = 0u; o.y = 0u; }
  *(uint2*)(y + (size_t)(b * S_ + s) * 512 + d0) = o;
}

// ---------------------------------------------------------------------------
// hy GEMM: hy[m,c] = sum_k y[m,k]*Whb[c,k] + bhb[c]; 64x64 tiles, 256 blocks.
__global__ __launch_bounds__(256)
void gemm_hy(const unsigned short* __restrict__ y, const unsigned short* __restrict__ Whb,
             const unsigned short* __restrict__ bhb, unsigned short* __restrict__ hy) {
  __shared__ __align__(16) unsigned short As[64 * 32];
  __shared__ __align__(16) unsigned short Bs[64 * 32];
  const int tid = threadIdx.x;
  const int w = tid >> 6, lane = tid & 63;
  const int l15 = lane & 15, l4 = lane >> 4;
  const int m0 = (blockIdx.x >> 3) * 64, c0 = (blockIdx.x & 7) * 64;
  const int srow = lane >> 2, scol = (lane & 3) * 8;

  f32x4 acc[4];
#pragma unroll
  for (int j = 0; j < 4; j++) acc[j] = (f32x4){0.f, 0.f, 0.f, 0.f};

  for (int kt = 0; kt < 512; kt += 32) {
    __syncthreads();
    gl_lds16(&As[(w * 16) * 32], y   + (size_t)(m0 + w * 16 + srow) * 512 + kt + scol);
    gl_lds16(&Bs[(w * 16) * 32], Whb + (size_t)(c0 + w * 16 + srow) * 512 + kt + scol);
    __syncthreads();
    bf16x8 a = *(const bf16x8*)&As[(w * 16 + l15) * 32 + l4 * 8];
#pragma unroll
    for (int j = 0; j < 4; j++) {
      bf16x8 bb = *(const bf16x8*)&Bs[(j * 16 + l15) * 32 + l4 * 8];
      acc[j] = __builtin_amdgcn_mfma_f32_16x16x32_bf16(a, bb, acc[j], 0, 0, 0);
    }
  }
#pragma unroll
  for (int j = 0; j < 4; j++) {
    const float bv = bf2f(bhb[c0 + j * 16 + l15]);
#pragma unroll
    for (int r = 0; r < 4; r++)
      hy[(size_t)(m0 + w * 16 + l4 * 4 + r) * 512 + c0 + j * 16 + l15] =
          f2bf(acc[j][r] + bv);
  }
}

// ---------------------------------------------------------------------------
// out[b,n,:] = hy[b*S + jx[n], :]; one wave per row, vectorized stores.
__global__ __launch_bounds__(256)
void gather_out(const unsigned short* __restrict__ hy, const int* __restrict__ jx,
                void* __restrict__ out, const int* __restrict__ flag) {
  const bool f32 = flag[0] != 0;
  const int gid  = blockIdx.x * 256 + threadIdx.x;
  const int wid  = gid >> 6;
  const int lane = gid & 63;
  const int b = wid >> 14;
  const int n = wid & (N_ - 1);
  const bool i64 = jx_is_i64(jx);
  const int s = seg_id(jx, n, i64);
  const bf16x8 v = *(const bf16x8*)(hy + (size_t)(b * S_ + s) * 512 + lane * 8);
  if (f32) {
    float* dst = (float*)out + (size_t)wid * 512 + lane * 8;
    float4 lo, hi;
    lo.x=bf2f((unsigned short)v[0]); lo.y=bf2f((unsigned short)v[1]);
    lo.z=bf2f((unsigned short)v[2]); lo.w=bf2f((unsigned short)v[3]);
    hi.x=bf2f((unsigned short)v[4]); hi.y=bf2f((unsigned short)v[5]);
    hi.z=bf2f((unsigned short)v[6]); hi.w=bf2f((unsigned short)v[7]);
    *(float4*)dst = lo;
    *(float4*)(dst + 4) = hi;
  } else {
    *(bf16x8*)((unsigned short*)out + (size_t)wid * 512 + lane * 8) = v;
  }
}

// ---------------------------------------------------------------------------
extern "C" void kernel_launch(void* const* d_in, const int* in_sizes, int n_in,
                              void* d_out, int out_size, void* d_ws, size_t ws_size,
                              hipStream_t stream) {
  const void* x  = d_in[0];
  const int* jx  = (const int*)d_in[1];
  const void* Wf = d_in[3];
  const void* bf = d_in[4];
  const void* Wg = d_in[5];
  const void* bg = d_in[6];
  const void* Wh = d_in[7];
  const void* bh = d_in[8];

  // EXACT R3-proven ws layout (ends at 72.4 MB; 80.8 MB was OOB).
  char* ws = (char*)d_ws;
  int* flag              = (int*)(ws + 0);
  int* segst             = (int*)(ws + 4096);
  unsigned short* biasfg = (unsigned short*)(ws + 8192);
  unsigned short* bhb    = (unsigned short*)(ws + 16384);
  unsigned short* Wfg    = (unsigned short*)(ws + 32768);      // 1 MB
  unsigned short* Whb    = (unsigned short*)(ws + 1081344);    // 0.5 MB
  unsigned short* y_ws   = (unsigned short*)(ws + 1605632);    // 2 MB
  unsigned short* hy_ws  = (unsigned short*)(ws + 3702784);    // 2 MB
  unsigned short* xb     = (unsigned short*)(ws + 8388608);    // 64 MB bf16 x
  // f/g (2 x 64 MB bf16) live in d_out (128 MB f32); dead before gather.
  unsigned short* fbuf   = (unsigned short*)d_out;
  unsigned short* gbuf   = (unsigned short*)d_out + (size_t)B_ * N_ * D_;

  classify_k<<<1, 256, 0, stream>>>(x, flag);
  prep_all<<<19465, 256, 0, stream>>>(x, jx, Wf, bf, Wg, bg, Wh, bh,
                                      xb, Wfg, biasfg, Whb, bhb, segst, flag);
  gemm_fg<<<4096, 256, 0, stream>>>(xb, Wfg, biasfg, fbuf, gbuf);
  seg_softmax<<<dim3(256, B_), 256, 0, stream>>>(fbuf, gbuf, segst, y_ws);
  gemm_hy<<<256, 256, 0, stream>>>(y_ws, Whb, bhb, hy_ws);
  gather_out<<<16384, 256, 0, stream>>>(hy_ws, jx, d_out, flag);
}